// Round 5
// baseline (4038.519 us; speedup 1.0000x reference)
//
#include <hip/hip_runtime.h>

// ---------------- problem constants ----------------
#define C_   64
#define U_   5
#define V_   5
#define H_   128
#define W_   128
#define NH_  4
#define HD_  16
#define WSZ  8
#define S_   64        // tokens per window
#define HW   16384     // H*W
#define UV   25        // U*V
#define POS  409600    // UV*HW, per-channel spatial size
#define TOT  26214400  // C_*POS
#define C4_  256

typedef unsigned short u16;
typedef unsigned int   u32;

// bf16 <-> fp32 helpers (raw bit manipulation, round-to-nearest-even)
__device__ __forceinline__ float us2f(u16 h){ return __uint_as_float(((u32)h)<<16); }
__device__ __forceinline__ u16 f2us(float f){
  u32 u = __float_as_uint(f);
  return (u16)((u + 0x7fffu + ((u>>16)&1u))>>16);
}
__device__ __forceinline__ void up2(u32 w, float&a, float&b){
  a = __uint_as_float(w<<16); b = __uint_as_float(w & 0xffff0000u);
}
__device__ __forceinline__ float silu_f(float x){ return x/(1.f+__expf(-x)); }

// ---------------- K1: LayerNorm over C (norm1) : x(f32) -> t(bf16, pools only) ----
__global__ __launch_bounds__(256,2) void k_ln1(const float* __restrict__ x,
                                               const float* __restrict__ w,
                                               const float* __restrict__ b,
                                               u16* __restrict__ t){
  int p = blockIdx.x*256 + threadIdx.x;        // 0..409599
  float v[64]; float s=0.f, sq=0.f;
  #pragma unroll
  for(int c=0;c<64;c++){ float f = x[c*POS+p]; v[c]=f; s+=f; sq+=f*f; }
  float mu = s*(1.f/64.f);
  float var = sq*(1.f/64.f) - mu*mu;
  float r = rsqrtf(var + 1e-5f);
  #pragma unroll
  for(int c=0;c<64;c++){
    t[c*POS+p] = f2us((v[c]-mu)*r*w[c] + b[c]);
  }
}

// ---------------- K7: LayerNorm over C (norm2) : x2(f32) -> t2(bf16) ----------------
__global__ __launch_bounds__(256,2) void k_ln2(const float* __restrict__ x2,
                                               const float* __restrict__ w,
                                               const float* __restrict__ b,
                                               u16* __restrict__ t2){
  int p = blockIdx.x*256 + threadIdx.x;
  float v[64]; float s=0.f, sq=0.f;
  #pragma unroll
  for(int c=0;c<64;c++){ float f = x2[c*POS+p]; v[c]=f; s+=f; sq+=f*f; }
  float mu = s*(1.f/64.f);
  float var = sq*(1.f/64.f) - mu*mu;
  float r = rsqrtf(var + 1e-5f);
  #pragma unroll
  for(int c=0;c<64;c++){
    t2[c*POS+p] = f2us((v[c]-mu)*r*w[c] + b[c]);
  }
}

// ---------------- K2a: pool over (u,v) -> P_hw[c][h][w] (raw sums) ----------------
__global__ void k_pool_hw(const u16* __restrict__ t, float* __restrict__ P){
  int idx = blockIdx.x*256 + threadIdx.x;      // < 64*16384
  int c = idx>>14, hw = idx & 16383;
  const u16* base = t + c*POS + hw;
  float s = 0.f;
  #pragma unroll
  for(int uv=0; uv<25; uv++) s += us2f(base[uv*HW]);
  P[idx] = s;
}

// ---------------- K2b: pool over (v,w) -> P_hu[c][u][h] ----------------
__global__ void k_pool_hu(const u16* __restrict__ t, float* __restrict__ P){
  int g = blockIdx.x*256 + threadIdx.x;
  int wid = g>>6, lane = g&63;                 // wid < 40960
  int c = wid/640, rem = wid - c*640;
  int u = rem>>7, h = rem&127;
  const u16* base = t + c*POS + u*5*HW + h*128;
  float s = 0.f;
  #pragma unroll
  for(int v=0;v<5;v++){ s += us2f(base[v*HW+lane]) + us2f(base[v*HW+lane+64]); }
  for(int off=32; off; off>>=1) s += __shfl_down(s, off);
  if(lane==0) P[wid] = s;
}

// ---------------- K2c: pool over (u,h) -> P_vw[c][v][w] (direct reduction) --------
__global__ void k_pool_vw(const u16* __restrict__ t, float* __restrict__ P){
  int bid = blockIdx.x;                        // 320 = 64*5
  int c = bid/5, v = bid - c*5;
  int w = threadIdx.x;                         // 128 threads
  float s = 0.f;
  for(int u=0;u<5;u++){
    const u16* base = t + c*POS + (u*5+v)*HW + w;
    for(int h=0;h<128;h++) s += us2f(base[h*128]);
  }
  P[(c*5+v)*128 + w] = s;
}

// ---------------- K2d: pool over (h,w) -> P_uv[c][u][v] ----------------
__global__ void k_pool_uv(const u16* __restrict__ t, float* __restrict__ P){
  int g = blockIdx.x*256 + threadIdx.x;
  int wid = g>>6, lane = g&63;                 // wid < 1600
  int c = wid/25, rem = wid - c*25;
  const u16* base = t + c*POS + rem*HW;
  float s = 0.f;
  #pragma unroll 8
  for(int k=0;k<256;k++) s += us2f(base[lane + k*64]);
  for(int off=32; off; off>>=1) s += __shfl_down(s, off);
  if(lane==0) P[wid] = s;
}

// ---------------- K3: MCA fused conv1 -> silu -> conv2 -> head conv -> fields ----------
__global__ __launch_bounds__(256,1) void k_mca(
    const float* __restrict__ Phw, const float* __restrict__ Phu,
    const float* __restrict__ Pvw, const float* __restrict__ Puv,
    const float* __restrict__ w1, const float* __restrict__ b1,
    const float* __restrict__ w2, const float* __restrict__ b2,
    const float* __restrict__ fw, const float* __restrict__ fb,
    float* __restrict__ F0, float* __restrict__ F1,
    float* __restrict__ F2, float* __restrict__ F3){
  __shared__ float W1s[4096], W2s[4096];
  for(int i=threadIdx.x;i<4096;i+=256){ W1s[i]=w1[i]; W2s[i]=w2[i]; }
  __syncthreads();
  int pos = blockIdx.x*256 + threadIdx.x;
  if(pos >= 133*133) return;
  int r = pos/133, cc = pos - r*133;

  float y1[64];
  #pragma unroll
  for(int o=0;o<64;o++) y1[o] = b1[o];
  for(int c=0;c<64;c++){
    float in;
    if(r<128){
      if(cc<128) in = Phw[(c<<14)+(r<<7)+cc]*(1.f/25.f);
      else       in = Phu[(c*5+(cc-128))*128 + r]*(1.f/640.f);
    } else {
      if(cc<128) in = Pvw[(c*5+(r-128))*128 + cc]*(1.f/640.f);
      else       in = Puv[c*25 + (cc-128)*5 + (r-128)]*(1.f/16384.f);
    }
    #pragma unroll
    for(int o=0;o<64;o++) y1[o] += W1s[o*64+c]*in;
  }
  float y2[64];
  #pragma unroll
  for(int o=0;o<64;o++) y2[o] = b2[o];
  for(int c=0;c<64;c++){
    float v = silu_f(y1[c]);
    #pragma unroll
    for(int o=0;o<64;o++) y2[o] += W2s[o*64+c]*v;
  }
  int hidx, idx0, stride_o; float* dst;
  if(r<128){
    if(cc<128){ hidx=0; dst=F0; idx0=(r<<7)+cc;            stride_o=16384; }
    else      { hidx=2; dst=F2; idx0=(cc-128)*128 + r;     stride_o=640;   }
  } else {
    if(cc<128){ hidx=3; dst=F3; idx0=(r-128)*128 + cc;     stride_o=640;   }
    else      { hidx=1; dst=F1; idx0=(cc-128)*5 + (r-128); stride_o=25;    }
  }
  const float* fwh = fw + hidx*4096;
  for(int o=0;o<64;o++){
    float f = fb[hidx*64+o];
    #pragma unroll
    for(int c=0;c<64;c++) f += fwh[o*64+c]*y2[c];
    dst[o*stride_o + idx0] = f;
  }
}

// ---------------- K5: attention bias gather -> Bt[h][key][query] ----------------
__global__ void k_bias(const int* __restrict__ rpi, const float* __restrict__ tab,
                       float* __restrict__ Bt){
  int idx = blockIdx.x*256 + threadIdx.x;      // < 4096, idx = i*64 + t (i=query)
  int i = idx>>6, tk = idx&63;
  int ri = rpi[idx];
  #pragma unroll
  for(int h=0;h<4;h++) Bt[h*4096 + tk*64 + i] = tab[ri*4+h];
}

// ---------------- K5b: pre-transpose qkv weights -> qkvT[(h*64+c)*48+dd] -------
__global__ void k_wt(const float* __restrict__ qkvw, float* __restrict__ qkvT){
  int i = blockIdx.x*256 + threadIdx.x;        // < 12288
  int h = i/3072, rem = i - h*3072;
  int c = rem/48, dd = rem - c*48;
  qkvT[i] = qkvw[(h*48+dd)*64 + c];
}

// ---------------- K4: x2 = x + LN1(x)*A  (fused-LN MCA combine, all fp32) -------
__global__ __launch_bounds__(256) void k_combine(
    const float* __restrict__ x,
    const float* __restrict__ n1w, const float* __restrict__ n1b,
    const float* __restrict__ F0, const float* __restrict__ F1,
    const float* __restrict__ F2, const float* __restrict__ F3,
    float* __restrict__ x2){
  int p = blockIdx.x*256 + threadIdx.x;        // < 409600
  float v[64]; float s=0.f, sq=0.f;
  #pragma unroll
  for(int c=0;c<64;c++){ float f = x[c*POS+p]; v[c]=f; s+=f; sq+=f*f; }
  float mu = s*(1.f/64.f);
  float r = rsqrtf(sq*(1.f/64.f) - mu*mu + 1e-5f);
  int uvi = p>>14, hw = p & 16383;
  int u = uvi/5, vv = uvi - 5*u;
  int h = hw>>7, w = hw & 127;
  #pragma unroll
  for(int c=0;c<64;c++){
    float t = (v[c]-mu)*r*n1w[c] + n1b[c];
    float A = F0[(c<<14)+hw] + F1[c*25+uvi] + F2[(c*5+u)*128+h] + F3[(c*5+vv)*128+w];
    x2[c*POS+p] = v[c] + t*A;
  }
}

// ---------------- K6: shifted window attention (fp32, in-kernel LN), += x2 ------
__global__ __launch_bounds__(256) void k_attn(
    const float* __restrict__ x,
    const float* __restrict__ n1w, const float* __restrict__ n1b,
    const float* __restrict__ qkvT, const float* __restrict__ qkvb,
    const float* __restrict__ projw, const float* __restrict__ projb,
    const float* __restrict__ Bt, float* __restrict__ x2){
  __shared__ float xws[64*68];                 // [tok][c] raw->normed, reused as ao
  __shared__ float kvu[8*64*16];               // [k/v][head][tok][d]
  __shared__ float ms[64], rs[64], wn[64], bn[64];
  int tid = threadIdx.x;
  int wid = blockIdx.x;
  int uv = wid>>8; int u = uv/5, v = uv - 5*u;
  int hb = (wid>>4)&15, wb = wid&15;
  const float* xbase = x + (u*5+v)*HW;

  if(tid<64){ wn[tid] = n1w[tid]; bn[tid] = n1b[tid]; }
  // stage raw x window (roll +4,+4 applied at gather)
  #pragma unroll
  for(int k2=0;k2<16;k2++){
    int lin = k2*256 + tid;
    int c = lin>>6, tok = lin&63;
    int ti = tok>>3, tj = tok&7;
    int hs = (hb*8+ti-4)&127, ws2 = (wb*8+tj-4)&127;
    xws[tok*68+c] = xbase[c*POS + hs*128 + ws2];
  }
  __syncthreads();
  // per-token LN stats
  if(tid<64){
    float s=0.f, sq=0.f;
    #pragma unroll
    for(int c=0;c<64;c++){ float f = xws[tid*68+c]; s+=f; sq+=f*f; }
    float mu = s*(1.f/64.f);
    ms[tid] = mu;
    rs[tid] = rsqrtf(sq*(1.f/64.f) - mu*mu + 1e-5f);
  }
  __syncthreads();
  // normalize in place
  #pragma unroll
  for(int k2=0;k2<16;k2++){
    int lin = k2*256 + tid;
    int c = lin>>6, tok = lin&63;
    xws[tok*68+c] = (xws[tok*68+c]-ms[tok])*rs[tok]*wn[c] + bn[c];
  }
  __syncthreads();                             // sync: tokens ready

  int h = tid>>6, lane = tid&63;               // head, token
  int hu_ = __builtin_amdgcn_readfirstlane(h); // wave-uniform head for weights
  float A[48];
  #pragma unroll
  for(int j=0;j<48;j++) A[j] = qkvb[hu_*48+j];
  const float* wT = qkvT + hu_*3072;           // [(c)*48+dd]
  for(int c=0;c<64;c++){
    float xc = xws[lane*68+c];
    const float* wr = wT + c*48;               // wave-uniform, cached
    #pragma unroll
    for(int j=0;j<48;j++) A[j] += xc*wr[j];
  }
  float q[16];
  #pragma unroll
  for(int d=0;d<16;d++) q[d] = A[d];
  #pragma unroll
  for(int d=0;d<16;d++){
    kvu[(h*64+lane)*16 + d]     = A[16+d];     // k
    kvu[((4+h)*64+lane)*16 + d] = A[32+d];     // v
  }
  __syncthreads();                             // kv ready; xws input no longer needed

  // scores + softmax (query = lane)
  float s[64]; float mx = -1e30f;
  #pragma unroll
  for(int tk=0;tk<64;tk++){
    const float4* kp = (const float4*)&kvu[(h*64+tk)*16];
    float a = 0.f;
    #pragma unroll
    for(int g4=0; g4<4; g4++){
      float4 kk = kp[g4];
      a += q[g4*4+0]*kk.x + q[g4*4+1]*kk.y + q[g4*4+2]*kk.z + q[g4*4+3]*kk.w;
    }
    a = a*0.25f + Bt[h*4096 + tk*64 + lane];
    s[tk] = a; mx = fmaxf(mx, a);
  }
  float l = 0.f;
  #pragma unroll
  for(int tk=0;tk<64;tk++){ float e = __expf(s[tk]-mx); s[tk]=e; l+=e; }
  float inv = 1.f/l;
  float o[16];
  #pragma unroll
  for(int d=0;d<16;d++) o[d] = 0.f;
  #pragma unroll
  for(int tk=0;tk<64;tk++){
    const float4* vp = (const float4*)&kvu[((4+h)*64+tk)*16];
    float pp = s[tk];
    #pragma unroll
    for(int g4=0; g4<4; g4++){
      float4 vv4 = vp[g4];
      o[g4*4+0] += pp*vv4.x; o[g4*4+1] += pp*vv4.y;
      o[g4*4+2] += pp*vv4.z; o[g4*4+3] += pp*vv4.w;
    }
  }
  #pragma unroll
  for(int d=0;d<16;d++) xws[lane*68 + h*16+d] = o[d]*inv;   // ao (c = h*16+d)
  __syncthreads();                             // ao ready

  // projection + scatter-add into x2 (inverse roll at write)
  int tok = tid&63, cg = tid>>6;
  int cgs = __builtin_amdgcn_readfirstlane(cg);
  float xin2[64];
  #pragma unroll
  for(int k2=0;k2<64;k2++) xin2[k2] = xws[tok*68+k2];
  int ti = tok>>3, tj = tok&7;
  int hf = (hb*8+ti-4)&127, wf_ = (wb*8+tj-4)&127;
  float* xb = x2 + (u*5+v)*HW + hf*128 + wf_;
  for(int cq=0;cq<16;cq++){
    int c = cgs*16+cq;
    float a = projb[c];
    const float* pw = projw + c*64;            // wave-uniform rows, cached
    #pragma unroll
    for(int k2=0;k2<64;k2++) a += xin2[k2]*pw[k2];
    xb[c*POS] += a;
  }
}

// ---------------- K8: fused MBConv + residual ------------------------------------
// CRITICAL reference semantic: _mbconv does x6.reshape(B*U*V, C, H, W) on a
// (B,C,U,V,H,W) tensor — a row-major REINTERPRETATION, not a transpose. Flat
// plane index p (plane = one HxW slice, p = c*25 + u*5 + v in memory order) is
// regrouped as p = n*64 + c2: batch n = p/64 convolves the 64 CONSECUTIVE flat
// planes [n*64, n*64+64), its "channel" c2 = p%64. So all plane addressing here
// uses (n*64+c)*HW, NOT c*POS + uv*HW.
// x2/out alias (both d_out); per-element read-then-write by same thread -> safe.
#define OCB 8
__global__ __launch_bounds__(256,2) void k_mbconv(
    const u16* __restrict__ t2, const float* x2,
    const float* __restrict__ w1, const float* __restrict__ b1,
    const float* __restrict__ dw, const float* __restrict__ db,
    const float* __restrict__ w2, const float* __restrict__ b2,
    float* out){
  __shared__ u16 t2s[400*66];                  // 20x20 halo tile, [pos][c]
  __shared__ u16 y1s[OCB*420];                 // expanded chunk on halo, [o][r*21+c]
  __shared__ float w1s[OCB*64];
  __shared__ float w2s[64*OCB];
  __shared__ float dws[OCB*25];
  int tid = threadIdx.x;
  int n = blockIdx.x>>6, tile = blockIdx.x&63;
  int h0 = (tile>>3)<<4, w0 = (tile&7)<<4;
  const u16* tb = t2 + n*64*HW;                // base of this batch's 64 flat planes

  for(int L=tid; L<25600; L+=256){
    int c = L/400, p = L - c*400;
    int r = p/20, cc = p - 20*r;
    int hh = h0-2+r, ww = w0-2+cc;
    u16 val = 0;
    if(((unsigned)hh < 128u) && ((unsigned)ww < 128u)) val = tb[c*HW + hh*128 + ww];
    t2s[p*66+c] = val;
  }
  float acc[64];
  #pragma unroll
  for(int c=0;c<64;c++) acc[c] = 0.f;
  int orow = tid>>4, ocol = tid&15;
  int og = tid>>5, pg = tid&31;
  __syncthreads();

  for(int oc0=0; oc0<256; oc0+=OCB){
    for(int i=tid;i<OCB*64;i+=256){ int o=i>>6, c=i&63; w1s[i] = w1[(oc0+o)*64+c]; }
    for(int i=tid;i<64*OCB;i+=256){ int c=i>>3, o=i&7; w2s[i] = w2[c*256 + oc0+o]; }
    if(tid < OCB*25){ int o=tid/25, k=tid-o*25; dws[tid] = dw[(oc0+o)*25+k]; }
    __syncthreads();

    // expand 1x1 + silu over halo; OOB positions yield 0 (post-silu zero pad)
    {
      float wr[64];
      #pragma unroll
      for(int c=0;c<64;c++) wr[c] = w1s[og*64+c];
      float bo = b1[oc0+og];
      for(int j=0;j<13;j++){
        int p = pg + 32*j;
        if(p<400){
          int rr = p/20, pc = p - 20*rr;
          int hh = h0-2+rr, ww = w0-2+pc;
          bool inimg = ((unsigned)hh < 128u) && ((unsigned)ww < 128u);
          const u32* row = (const u32*)(t2s + p*66);
          float a = bo;
          #pragma unroll
          for(int c2=0;c2<32;c2++){
            float xa, xb; up2(row[c2], xa, xb);
            a += wr[2*c2]*xa + wr[2*c2+1]*xb;
          }
          y1s[og*420 + rr*21 + pc] = inimg ? f2us(silu_f(a)) : (u16)0;
        }
      }
    }
    __syncthreads();

    // depthwise 5x5 + silu, then project accumulate
    float y2r[OCB];
    #pragma unroll
    for(int o=0;o<OCB;o++){
      float s = 0.f;
      #pragma unroll
      for(int kh=0;kh<5;kh++){
        #pragma unroll
        for(int kw=0;kw<5;kw++)
          s += us2f(y1s[o*420 + (orow+kh)*21 + (ocol+kw)]) * dws[o*25 + kh*5 + kw];
      }
      y2r[o] = silu_f(s + db[oc0+o]);
    }
    #pragma unroll 8
    for(int c=0;c<64;c++){
      const float4* wp = (const float4*)(w2s + c*OCB);
      float4 wa = wp[0], wb = wp[1];
      acc[c] += wa.x*y2r[0]+wa.y*y2r[1]+wa.z*y2r[2]+wa.w*y2r[3]
              + wb.x*y2r[4]+wb.y*y2r[5]+wb.z*y2r[6]+wb.w*y2r[7];
    }
    __syncthreads();
  }
  int gb = (h0+orow)*128 + (w0+ocol);
  for(int c=0;c<64;c++){
    int g = (n*64+c)*HW + gb;                  // reshaped plane addressing
    out[g] = acc[c] + b2[c] + x2[g];
  }
}

// ---------------- workspace layout (bytes), total 61,600,256 ----------------
static const size_t OFF_T   = 0;             // u16  t / t2 (reused)   52,428,800
static const size_t OFF_PHW = 52428800;      // f32  pool hw            4,194,304
static const size_t OFF_PHU = 56623104;      // f32  pool hu              163,840
static const size_t OFF_PVW = 56786944;      // f32  pool vw              163,840
static const size_t OFF_PUV = 56950784;      // f32  pool uv                6,400
static const size_t OFF_F0  = 56957184;      // f32  field hw           4,194,304
static const size_t OFF_F2  = 61151488;      // f32  field uh             163,840
static const size_t OFF_F3  = 61315328;      // f32  field vw             163,840
static const size_t OFF_F1  = 61479168;      // f32  field uv               6,400
static const size_t OFF_BT  = 61485568;      // f32  attn bias             65,536
static const size_t OFF_QT  = 61551104;      // f32  qkvT                  49,152

extern "C" void kernel_launch(void* const* d_in, const int* in_sizes, int n_in,
                              void* d_out, int out_size, void* d_ws, size_t ws_size,
                              hipStream_t stream){
  (void)in_sizes; (void)n_in; (void)out_size; (void)ws_size;
  const float* x     = (const float*)d_in[0];
  const float* n1w   = (const float*)d_in[1];
  const float* n1b   = (const float*)d_in[2];
  const float* n2w   = (const float*)d_in[3];
  const float* n2b   = (const float*)d_in[4];
  const float* qkvw  = (const float*)d_in[5];
  const float* qkvb  = (const float*)d_in[6];
  const float* projw = (const float*)d_in[7];
  const float* projb = (const float*)d_in[8];
  const float* rpbt  = (const float*)d_in[9];
  const int*   rpi   = (const int*)d_in[10];
  const float* mw1   = (const float*)d_in[11];
  const float* mb1   = (const float*)d_in[12];
  const float* mw2   = (const float*)d_in[13];
  const float* mb2   = (const float*)d_in[14];
  const float* mfw   = (const float*)d_in[15];
  const float* mfb   = (const float*)d_in[16];
  const float* bw1   = (const float*)d_in[17];
  const float* bb1   = (const float*)d_in[18];
  const float* bdw   = (const float*)d_in[19];
  const float* bdb   = (const float*)d_in[20];
  const float* bw2   = (const float*)d_in[21];
  const float* bb2   = (const float*)d_in[22];

  char* ws = (char*)d_ws;
  u16*   t   = (u16*)  (ws + OFF_T);
  float* Phw = (float*)(ws + OFF_PHW);
  float* Phu = (float*)(ws + OFF_PHU);
  float* Pvw = (float*)(ws + OFF_PVW);
  float* Puv = (float*)(ws + OFF_PUV);
  float* F0  = (float*)(ws + OFF_F0);
  float* F1  = (float*)(ws + OFF_F1);
  float* F2  = (float*)(ws + OFF_F2);
  float* F3  = (float*)(ws + OFF_F3);
  float* Bt  = (float*)(ws + OFF_BT);
  float* qT  = (float*)(ws + OFF_QT);
  float* x2  = (float*)d_out;    // f32 residual accumulator lives in d_out
  float* outp= (float*)d_out;

  // 1) t = LN1(x) (bf16, pool consumption only)
  k_ln1<<<1600,256,0,stream>>>(x, n1w, n1b, t);
  // 2) pools of t
  k_pool_hw<<<4096,256,0,stream>>>(t, Phw);
  k_pool_hu<<<10240,256,0,stream>>>(t, Phu);
  k_pool_vw<<<320,128,0,stream>>>(t, Pvw);
  k_pool_uv<<<400,256,0,stream>>>(t, Puv);
  // 3) MCA convs -> gate fields
  k_mca<<<70,256,0,stream>>>(Phw,Phu,Pvw,Puv, mw1,mb1,mw2,mb2, mfw,mfb, F0,F1,F2,F3);
  // 4) attention bias table + qkv weight transpose
  k_bias<<<16,256,0,stream>>>(rpi, rpbt, Bt);
  k_wt<<<48,256,0,stream>>>(qkvw, qT);
  // 5) x2 = x + LN1(x)*A  (fused LN, pure write of all of d_out)
  k_combine<<<1600,256,0,stream>>>(x, n1w, n1b, F0,F1,F2,F3, x2);
  // 6) x2 += window_attn(LN1(x))  (fp32, in-kernel LN; unique-writer RMW)
  k_attn<<<6400,256,0,stream>>>(x, n1w, n1b, qT, qkvb, projw, projb, Bt, x2);
  // 7) t2 = LN2(x2)   (t buffer reused)
  k_ln2<<<1600,256,0,stream>>>(x2, n2w, n2b, t);
  // 8) out = x2 + mbconv(t2)  (reshaped-plane grouping, in-place on d_out)
  k_mbconv<<<1600,256,0,stream>>>(t, x2, bw1,bb1, bdw,bdb, bw2,bb2, outp);
}

// Round 6
// 3182.127 us; speedup vs baseline: 1.2691x; 1.2691x over previous
//
#include <hip/hip_runtime.h>

// ---------------- problem constants ----------------
#define C_   64
#define U_   5
#define V_   5
#define H_   128
#define W_   128
#define NH_  4
#define HD_  16
#define WSZ  8
#define S_   64        // tokens per window
#define HW   16384     // H*W
#define UV   25        // U*V
#define POS  409600    // UV*HW, per-channel spatial size
#define TOT  26214400  // C_*POS
#define C4_  256

typedef unsigned short u16;
typedef unsigned int   u32;

// bf16 <-> fp32 helpers (raw bit manipulation, round-to-nearest-even)
__device__ __forceinline__ float us2f(u16 h){ return __uint_as_float(((u32)h)<<16); }
__device__ __forceinline__ u16 f2us(float f){
  u32 u = __float_as_uint(f);
  return (u16)((u + 0x7fffu + ((u>>16)&1u))>>16);
}
__device__ __forceinline__ void up2(u32 w, float&a, float&b){
  a = __uint_as_float(w<<16); b = __uint_as_float(w & 0xffff0000u);
}
__device__ __forceinline__ void up8(uint4 uu, float* f){
  up2(uu.x,f[0],f[1]); up2(uu.y,f[2],f[3]); up2(uu.z,f[4],f[5]); up2(uu.w,f[6],f[7]);
}
__device__ __forceinline__ float silu_f(float x){ return x/(1.f+__expf(-x)); }

// ---------------- K1: LayerNorm over C (norm1) : x(f32) -> t(bf16, pools only) ----
__global__ __launch_bounds__(256,2) void k_ln1(const float* __restrict__ x,
                                               const float* __restrict__ w,
                                               const float* __restrict__ b,
                                               u16* __restrict__ t){
  int p = blockIdx.x*256 + threadIdx.x;        // 0..409599
  float v[64]; float s=0.f, sq=0.f;
  #pragma unroll
  for(int c=0;c<64;c++){ float f = x[c*POS+p]; v[c]=f; s+=f; sq+=f*f; }
  float mu = s*(1.f/64.f);
  float var = sq*(1.f/64.f) - mu*mu;
  float r = rsqrtf(var + 1e-5f);
  #pragma unroll
  for(int c=0;c<64;c++){
    t[c*POS+p] = f2us((v[c]-mu)*r*w[c] + b[c]);
  }
}

// ---------------- K7: LayerNorm over C (norm2) : x2(f32) -> t2(bf16) ----------------
__global__ __launch_bounds__(256,2) void k_ln2(const float* __restrict__ x2,
                                               const float* __restrict__ w,
                                               const float* __restrict__ b,
                                               u16* __restrict__ t2){
  int p = blockIdx.x*256 + threadIdx.x;
  float v[64]; float s=0.f, sq=0.f;
  #pragma unroll
  for(int c=0;c<64;c++){ float f = x2[c*POS+p]; v[c]=f; s+=f; sq+=f*f; }
  float mu = s*(1.f/64.f);
  float var = sq*(1.f/64.f) - mu*mu;
  float r = rsqrtf(var + 1e-5f);
  #pragma unroll
  for(int c=0;c<64;c++){
    t2[c*POS+p] = f2us((v[c]-mu)*r*w[c] + b[c]);
  }
}

// ---------------- K2a: pool over (u,v) -> P_hw[c][h][w] (raw sums) ----------------
__global__ void k_pool_hw(const u16* __restrict__ t, float* __restrict__ P){
  int idx = blockIdx.x*256 + threadIdx.x;      // < 64*16384
  int c = idx>>14, hw = idx & 16383;
  const u16* base = t + c*POS + hw;
  float s = 0.f;
  #pragma unroll
  for(int uv=0; uv<25; uv++) s += us2f(base[uv*HW]);
  P[idx] = s;
}

// ---------------- K2b: pool over (v,w) -> P_hu[c][u][h] ----------------
__global__ void k_pool_hu(const u16* __restrict__ t, float* __restrict__ P){
  int g = blockIdx.x*256 + threadIdx.x;
  int wid = g>>6, lane = g&63;                 // wid < 40960
  int c = wid/640, rem = wid - c*640;
  int u = rem>>7, h = rem&127;
  const u16* base = t + c*POS + u*5*HW + h*128;
  float s = 0.f;
  #pragma unroll
  for(int v=0;v<5;v++){ s += us2f(base[v*HW+lane]) + us2f(base[v*HW+lane+64]); }
  for(int off=32; off; off>>=1) s += __shfl_down(s, off);
  if(lane==0) P[wid] = s;
}

// ---------------- K2c: pool over (u,h) -> P_vw[c][v][w] (direct reduction) --------
__global__ void k_pool_vw(const u16* __restrict__ t, float* __restrict__ P){
  int bid = blockIdx.x;                        // 320 = 64*5
  int c = bid/5, v = bid - c*5;
  int w = threadIdx.x;                         // 128 threads
  float s = 0.f;
  for(int u=0;u<5;u++){
    const u16* base = t + c*POS + (u*5+v)*HW + w;
    for(int h=0;h<128;h++) s += us2f(base[h*128]);
  }
  P[(c*5+v)*128 + w] = s;
}

// ---------------- K2d: pool over (h,w) -> P_uv[c][u][v] ----------------
__global__ void k_pool_uv(const u16* __restrict__ t, float* __restrict__ P){
  int g = blockIdx.x*256 + threadIdx.x;
  int wid = g>>6, lane = g&63;                 // wid < 1600
  int c = wid/25, rem = wid - c*25;
  const u16* base = t + c*POS + rem*HW;
  float s = 0.f;
  #pragma unroll 8
  for(int k=0;k<256;k++) s += us2f(base[lane + k*64]);
  for(int off=32; off; off>>=1) s += __shfl_down(s, off);
  if(lane==0) P[wid] = s;
}

// ---------------- K3: MCA fused conv1 -> silu -> conv2 -> head conv -> fields ----------
__global__ __launch_bounds__(256,1) void k_mca(
    const float* __restrict__ Phw, const float* __restrict__ Phu,
    const float* __restrict__ Pvw, const float* __restrict__ Puv,
    const float* __restrict__ w1, const float* __restrict__ b1,
    const float* __restrict__ w2, const float* __restrict__ b2,
    const float* __restrict__ fw, const float* __restrict__ fb,
    float* __restrict__ F0, float* __restrict__ F1,
    float* __restrict__ F2, float* __restrict__ F3){
  __shared__ float W1s[4096], W2s[4096];
  for(int i=threadIdx.x;i<4096;i+=256){ W1s[i]=w1[i]; W2s[i]=w2[i]; }
  __syncthreads();
  int pos = blockIdx.x*256 + threadIdx.x;
  if(pos >= 133*133) return;
  int r = pos/133, cc = pos - r*133;

  float y1[64];
  #pragma unroll
  for(int o=0;o<64;o++) y1[o] = b1[o];
  for(int c=0;c<64;c++){
    float in;
    if(r<128){
      if(cc<128) in = Phw[(c<<14)+(r<<7)+cc]*(1.f/25.f);
      else       in = Phu[(c*5+(cc-128))*128 + r]*(1.f/640.f);
    } else {
      if(cc<128) in = Pvw[(c*5+(r-128))*128 + cc]*(1.f/640.f);
      else       in = Puv[c*25 + (cc-128)*5 + (r-128)]*(1.f/16384.f);
    }
    #pragma unroll
    for(int o=0;o<64;o++) y1[o] += W1s[o*64+c]*in;
  }
  float y2[64];
  #pragma unroll
  for(int o=0;o<64;o++) y2[o] = b2[o];
  for(int c=0;c<64;c++){
    float v = silu_f(y1[c]);
    #pragma unroll
    for(int o=0;o<64;o++) y2[o] += W2s[o*64+c]*v;
  }
  int hidx, idx0, stride_o; float* dst;
  if(r<128){
    if(cc<128){ hidx=0; dst=F0; idx0=(r<<7)+cc;            stride_o=16384; }
    else      { hidx=2; dst=F2; idx0=(cc-128)*128 + r;     stride_o=640;   }
  } else {
    if(cc<128){ hidx=3; dst=F3; idx0=(r-128)*128 + cc;     stride_o=640;   }
    else      { hidx=1; dst=F1; idx0=(cc-128)*5 + (r-128); stride_o=25;    }
  }
  const float* fwh = fw + hidx*4096;
  for(int o=0;o<64;o++){
    float f = fb[hidx*64+o];
    #pragma unroll
    for(int c=0;c<64;c++) f += fwh[o*64+c]*y2[c];
    dst[o*stride_o + idx0] = f;
  }
}

// ---------------- K5: attention bias gather -> Bt[h][key][query] ----------------
__global__ void k_bias(const int* __restrict__ rpi, const float* __restrict__ tab,
                       float* __restrict__ Bt){
  int idx = blockIdx.x*256 + threadIdx.x;      // < 4096, idx = i*64 + t (i=query)
  int i = idx>>6, tk = idx&63;
  int ri = rpi[idx];
  #pragma unroll
  for(int h=0;h<4;h++) Bt[h*4096 + tk*64 + i] = tab[ri*4+h];
}

// ---------------- K5b: pre-transpose qkv weights -> qkvT[(h*64+c)*48+dd] -------
__global__ void k_wt(const float* __restrict__ qkvw, float* __restrict__ qkvT){
  int i = blockIdx.x*256 + threadIdx.x;        // < 12288
  int h = i/3072, rem = i - h*3072;
  int c = rem/48, dd = rem - c*48;
  qkvT[i] = qkvw[(h*48+dd)*64 + c];
}

// ---------------- K4: x2 = x + LN1(x)*A  (fused-LN MCA combine, all fp32) -------
__global__ __launch_bounds__(256) void k_combine(
    const float* __restrict__ x,
    const float* __restrict__ n1w, const float* __restrict__ n1b,
    const float* __restrict__ F0, const float* __restrict__ F1,
    const float* __restrict__ F2, const float* __restrict__ F3,
    float* __restrict__ x2){
  int p = blockIdx.x*256 + threadIdx.x;        // < 409600
  float v[64]; float s=0.f, sq=0.f;
  #pragma unroll
  for(int c=0;c<64;c++){ float f = x[c*POS+p]; v[c]=f; s+=f; sq+=f*f; }
  float mu = s*(1.f/64.f);
  float r = rsqrtf(sq*(1.f/64.f) - mu*mu + 1e-5f);
  int uvi = p>>14, hw = p & 16383;
  int u = uvi/5, vv = uvi - 5*u;
  int h = hw>>7, w = hw & 127;
  #pragma unroll
  for(int c=0;c<64;c++){
    float t = (v[c]-mu)*r*n1w[c] + n1b[c];
    float A = F0[(c<<14)+hw] + F1[c*25+uvi] + F2[(c*5+u)*128+h] + F3[(c*5+vv)*128+w];
    x2[c*POS+p] = v[c] + t*A;
  }
}

// ---------------- K6: shifted window attention (fp32, in-kernel LN), += x2 ------
__global__ __launch_bounds__(256) void k_attn(
    const float* __restrict__ x,
    const float* __restrict__ n1w, const float* __restrict__ n1b,
    const float* __restrict__ qkvT, const float* __restrict__ qkvb,
    const float* __restrict__ projw, const float* __restrict__ projb,
    const float* __restrict__ Bt, float* __restrict__ x2){
  __shared__ float xws[64*68];                 // [tok][c] raw->normed, reused as ao
  __shared__ float kvu[8*64*16];               // [k/v][head][tok][d]
  __shared__ float ms[64], rs[64], wn[64], bn[64];
  int tid = threadIdx.x;
  int wid = blockIdx.x;
  int uv = wid>>8; int u = uv/5, v = uv - 5*u;
  int hb = (wid>>4)&15, wb = wid&15;
  const float* xbase = x + (u*5+v)*HW;

  if(tid<64){ wn[tid] = n1w[tid]; bn[tid] = n1b[tid]; }
  // stage raw x window (roll +4,+4 applied at gather)
  #pragma unroll
  for(int k2=0;k2<16;k2++){
    int lin = k2*256 + tid;
    int c = lin>>6, tok = lin&63;
    int ti = tok>>3, tj = tok&7;
    int hs = (hb*8+ti-4)&127, ws2 = (wb*8+tj-4)&127;
    xws[tok*68+c] = xbase[c*POS + hs*128 + ws2];
  }
  __syncthreads();
  // per-token LN stats
  if(tid<64){
    float s=0.f, sq=0.f;
    #pragma unroll
    for(int c=0;c<64;c++){ float f = xws[tid*68+c]; s+=f; sq+=f*f; }
    float mu = s*(1.f/64.f);
    ms[tid] = mu;
    rs[tid] = rsqrtf(sq*(1.f/64.f) - mu*mu + 1e-5f);
  }
  __syncthreads();
  // normalize in place
  #pragma unroll
  for(int k2=0;k2<16;k2++){
    int lin = k2*256 + tid;
    int c = lin>>6, tok = lin&63;
    xws[tok*68+c] = (xws[tok*68+c]-ms[tok])*rs[tok]*wn[c] + bn[c];
  }
  __syncthreads();                             // sync: tokens ready

  int h = tid>>6, lane = tid&63;               // head, token
  int hu_ = __builtin_amdgcn_readfirstlane(h); // wave-uniform head for weights
  float A[48];
  #pragma unroll
  for(int j=0;j<48;j++) A[j] = qkvb[hu_*48+j];
  const float* wT = qkvT + hu_*3072;           // [(c)*48+dd]
  for(int c=0;c<64;c++){
    float xc = xws[lane*68+c];
    const float* wr = wT + c*48;               // wave-uniform, cached
    #pragma unroll
    for(int j=0;j<48;j++) A[j] += xc*wr[j];
  }
  float q[16];
  #pragma unroll
  for(int d=0;d<16;d++) q[d] = A[d];
  #pragma unroll
  for(int d=0;d<16;d++){
    kvu[(h*64+lane)*16 + d]     = A[16+d];     // k
    kvu[((4+h)*64+lane)*16 + d] = A[32+d];     // v
  }
  __syncthreads();                             // kv ready; xws input no longer needed

  // scores + softmax (query = lane)
  float s[64]; float mx = -1e30f;
  #pragma unroll
  for(int tk=0;tk<64;tk++){
    const float4* kp = (const float4*)&kvu[(h*64+tk)*16];
    float a = 0.f;
    #pragma unroll
    for(int g4=0; g4<4; g4++){
      float4 kk = kp[g4];
      a += q[g4*4+0]*kk.x + q[g4*4+1]*kk.y + q[g4*4+2]*kk.z + q[g4*4+3]*kk.w;
    }
    a = a*0.25f + Bt[h*4096 + tk*64 + lane];
    s[tk] = a; mx = fmaxf(mx, a);
  }
  float l = 0.f;
  #pragma unroll
  for(int tk=0;tk<64;tk++){ float e = __expf(s[tk]-mx); s[tk]=e; l+=e; }
  float inv = 1.f/l;
  float o[16];
  #pragma unroll
  for(int d=0;d<16;d++) o[d] = 0.f;
  #pragma unroll
  for(int tk=0;tk<64;tk++){
    const float4* vp = (const float4*)&kvu[((4+h)*64+tk)*16];
    float pp = s[tk];
    #pragma unroll
    for(int g4=0; g4<4; g4++){
      float4 vv4 = vp[g4];
      o[g4*4+0] += pp*vv4.x; o[g4*4+1] += pp*vv4.y;
      o[g4*4+2] += pp*vv4.z; o[g4*4+3] += pp*vv4.w;
    }
  }
  #pragma unroll
  for(int d=0;d<16;d++) xws[lane*68 + h*16+d] = o[d]*inv;   // ao (c = h*16+d)
  __syncthreads();                             // ao ready

  // projection + scatter-add into x2 (inverse roll at write)
  int tok = tid&63, cg = tid>>6;
  int cgs = __builtin_amdgcn_readfirstlane(cg);
  float xin2[64];
  #pragma unroll
  for(int k2=0;k2<64;k2++) xin2[k2] = xws[tok*68+k2];
  int ti = tok>>3, tj = tok&7;
  int hf = (hb*8+ti-4)&127, wf_ = (wb*8+tj-4)&127;
  float* xb = x2 + (u*5+v)*HW + hf*128 + wf_;
  for(int cq=0;cq<16;cq++){
    int c = cgs*16+cq;
    float a = projb[c];
    const float* pw = projw + c*64;            // wave-uniform rows, cached
    #pragma unroll
    for(int k2=0;k2<64;k2++) a += xin2[k2]*pw[k2];
    xb[c*POS] += a;
  }
}

// ---------------- K8 v2: fused MBConv + residual, spill-free -------------------
// Reference semantic (verified round 5): x6.reshape(B*U*V, C, H, W) is a flat
// plane regrouping — batch n uses planes [n*64, n*64+64). Addressing (n*64+c)*HW.
// v2 design: 8x8 output tile, 12x12 halo, 256 threads = 64 pixels x 4 cgroups.
// Per-thread accumulator is acc[16] (was acc[64] -> scratch spill, 3.3 GB/launch).
// y2 shared via LDS; expand reads halo rows via 16B-aligned ds_read_b128.
#define OCB 16
__global__ __launch_bounds__(256,4) void k_mbconv(
    const u16* __restrict__ t2, const float* x2,
    const float* __restrict__ w1, const float* __restrict__ b1,
    const float* __restrict__ dw, const float* __restrict__ db,
    const float* __restrict__ w2, const float* __restrict__ b2,
    float* out){
  __shared__ u16  t2s[144*72];     // 12x12 halo, [p][c], row=144B (16B aligned)
  __shared__ u16  y1s[OCB*145];    // expanded+silu on halo, [o][p]
  __shared__ float y2s[64*17];     // dw+silu output, [pix][o] padded
  __shared__ float w2s[64*OCB];    // [c][o]
  __shared__ float dws[OCB*25];
  int tid = threadIdx.x;
  int n = blockIdx.x >> 8, tile = blockIdx.x & 255;   // 25 batches x 256 tiles
  int h0 = (tile>>4)<<3, w0 = (tile&15)<<3;
  const u16* tb = t2 + n*64*HW;

  // stage halo tile (144 pos x 64 ch)
  for(int L=tid; L<9216; L+=256){
    int c = L/144, p = L - c*144;
    int rr = p/12, pc = p - rr*12;
    int hh = h0-2+rr, ww = w0-2+pc;
    u16 val = 0;
    if(((unsigned)hh<128u)&&((unsigned)ww<128u)) val = tb[c*HW + hh*128 + ww];
    t2s[p*72 + c] = val;
  }
  float acc[16];
  #pragma unroll
  for(int i=0;i<16;i++) acc[i]=0.f;
  int pix = tid & 63, cg = tid >> 6;   // dw/proj mapping
  int r = pix>>3, cc = pix&7;
  int og = tid >> 4, pg = tid & 15;    // expand mapping (16 och x 16 pos-lanes)
  __syncthreads();

  for(int oc0=0; oc0<256; oc0+=OCB){
    // stage w2 chunk + dw chunk (guarded from prev proj by loop-end sync)
    for(int i=tid;i<64*OCB;i+=256){ int c=i>>4, o=i&15; w2s[i] = w2[c*256 + oc0 + o]; }
    for(int i=tid;i<OCB*25;i+=256) dws[i] = dw[oc0*25 + i];
    __syncthreads();

    // expand 1x1 + silu on halo: thread (og,pg) does positions pg+16j, j<9
    {
      float wr[64];
      const float4* wrow = (const float4*)(w1 + (oc0+og)*64);  // L2-resident
      #pragma unroll
      for(int q=0;q<16;q++){
        float4 f4 = wrow[q];
        wr[4*q]=f4.x; wr[4*q+1]=f4.y; wr[4*q+2]=f4.z; wr[4*q+3]=f4.w;
      }
      float bo = b1[oc0+og];
      #pragma unroll
      for(int j=0;j<9;j++){
        int p = pg + 16*j;
        int rr = p/12, pc = p - rr*12;
        int hh = h0-2+rr, ww = w0-2+pc;
        bool inimg = ((unsigned)hh<128u)&&((unsigned)ww<128u);
        const uint4* row = (const uint4*)(t2s + p*72);
        float a = bo;
        #pragma unroll
        for(int q=0;q<8;q++){
          uint4 uu = row[q];
          float f[8]; up8(uu,f);
          #pragma unroll
          for(int k=0;k<8;k++) a += wr[8*q+k]*f[k];
        }
        y1s[og*145 + p] = inimg ? f2us(silu_f(a)) : (u16)0;  // post-silu zero pad
      }
    }
    __syncthreads();

    // depthwise 5x5 + silu -> y2s: thread (pix,cg) does o = cg+4*qq
    #pragma unroll
    for(int qq=0;qq<4;qq++){
      int o = cg + 4*qq;
      float s = 0.f;
      #pragma unroll
      for(int kh=0;kh<5;kh++){
        #pragma unroll
        for(int kw=0;kw<5;kw++)
          s += us2f(y1s[o*145 + (r+kh)*12 + (cc+kw)]) * dws[o*25 + kh*5 + kw];
      }
      y2s[pix*17 + o] = silu_f(s + db[oc0+o]);
    }
    __syncthreads();

    // project: thread (pix,cg) accumulates 16 output channels for its pixel
    #pragma unroll
    for(int o=0;o<OCB;o++){
      float yv = y2s[pix*17 + o];
      #pragma unroll
      for(int cq=0;cq<16;cq++)
        acc[cq] += w2s[(cg*16+cq)*OCB + o] * yv;
    }
    __syncthreads();
  }
  int gb = (h0+r)*128 + (w0+cc);
  #pragma unroll
  for(int cq=0;cq<16;cq++){
    int c = cg*16+cq;
    int g = (n*64+c)*HW + gb;
    out[g] = acc[cq] + b2[c] + x2[g];
  }
}

// ---------------- workspace layout (bytes), total 61,600,256 ----------------
static const size_t OFF_T   = 0;             // u16  t / t2 (reused)   52,428,800
static const size_t OFF_PHW = 52428800;      // f32  pool hw            4,194,304
static const size_t OFF_PHU = 56623104;      // f32  pool hu              163,840
static const size_t OFF_PVW = 56786944;      // f32  pool vw              163,840
static const size_t OFF_PUV = 56950784;      // f32  pool uv                6,400
static const size_t OFF_F0  = 56957184;      // f32  field hw           4,194,304
static const size_t OFF_F2  = 61151488;      // f32  field uh             163,840
static const size_t OFF_F3  = 61315328;      // f32  field vw             163,840
static const size_t OFF_F1  = 61479168;      // f32  field uv               6,400
static const size_t OFF_BT  = 61485568;      // f32  attn bias             65,536
static const size_t OFF_QT  = 61551104;      // f32  qkvT                  49,152

extern "C" void kernel_launch(void* const* d_in, const int* in_sizes, int n_in,
                              void* d_out, int out_size, void* d_ws, size_t ws_size,
                              hipStream_t stream){
  (void)in_sizes; (void)n_in; (void)out_size; (void)ws_size;
  const float* x     = (const float*)d_in[0];
  const float* n1w   = (const float*)d_in[1];
  const float* n1b   = (const float*)d_in[2];
  const float* n2w   = (const float*)d_in[3];
  const float* n2b   = (const float*)d_in[4];
  const float* qkvw  = (const float*)d_in[5];
  const float* qkvb  = (const float*)d_in[6];
  const float* projw = (const float*)d_in[7];
  const float* projb = (const float*)d_in[8];
  const float* rpbt  = (const float*)d_in[9];
  const int*   rpi   = (const int*)d_in[10];
  const float* mw1   = (const float*)d_in[11];
  const float* mb1   = (const float*)d_in[12];
  const float* mw2   = (const float*)d_in[13];
  const float* mb2   = (const float*)d_in[14];
  const float* mfw   = (const float*)d_in[15];
  const float* mfb   = (const float*)d_in[16];
  const float* bw1   = (const float*)d_in[17];
  const float* bb1   = (const float*)d_in[18];
  const float* bdw   = (const float*)d_in[19];
  const float* bdb   = (const float*)d_in[20];
  const float* bw2   = (const float*)d_in[21];
  const float* bb2   = (const float*)d_in[22];

  char* ws = (char*)d_ws;
  u16*   t   = (u16*)  (ws + OFF_T);
  float* Phw = (float*)(ws + OFF_PHW);
  float* Phu = (float*)(ws + OFF_PHU);
  float* Pvw = (float*)(ws + OFF_PVW);
  float* Puv = (float*)(ws + OFF_PUV);
  float* F0  = (float*)(ws + OFF_F0);
  float* F1  = (float*)(ws + OFF_F1);
  float* F2  = (float*)(ws + OFF_F2);
  float* F3  = (float*)(ws + OFF_F3);
  float* Bt  = (float*)(ws + OFF_BT);
  float* qT  = (float*)(ws + OFF_QT);
  float* x2  = (float*)d_out;    // f32 residual accumulator lives in d_out
  float* outp= (float*)d_out;

  // 1) t = LN1(x) (bf16, pool consumption only)
  k_ln1<<<1600,256,0,stream>>>(x, n1w, n1b, t);
  // 2) pools of t
  k_pool_hw<<<4096,256,0,stream>>>(t, Phw);
  k_pool_hu<<<10240,256,0,stream>>>(t, Phu);
  k_pool_vw<<<320,128,0,stream>>>(t, Pvw);
  k_pool_uv<<<400,256,0,stream>>>(t, Puv);
  // 3) MCA convs -> gate fields
  k_mca<<<70,256,0,stream>>>(Phw,Phu,Pvw,Puv, mw1,mb1,mw2,mb2, mfw,mfb, F0,F1,F2,F3);
  // 4) attention bias table + qkv weight transpose
  k_bias<<<16,256,0,stream>>>(rpi, rpbt, Bt);
  k_wt<<<48,256,0,stream>>>(qkvw, qT);
  // 5) x2 = x + LN1(x)*A  (fused LN, pure write of all of d_out)
  k_combine<<<1600,256,0,stream>>>(x, n1w, n1b, F0,F1,F2,F3, x2);
  // 6) x2 += window_attn(LN1(x))  (fp32, in-kernel LN; unique-writer RMW)
  k_attn<<<6400,256,0,stream>>>(x, n1w, n1b, qT, qkvb, projw, projb, Bt, x2);
  // 7) t2 = LN2(x2)   (t buffer reused)
  k_ln2<<<1600,256,0,stream>>>(x2, n2w, n2b, t);
  // 8) out = x2 + mbconv(t2)  (8x8-tile spill-free v2, in-place on d_out)
  k_mbconv<<<6400,256,0,stream>>>(t, x2, bw1,bb1, bdw,bdb, bw2,bb2, outp);
}

// Round 7
// 2748.130 us; speedup vs baseline: 1.4696x; 1.1579x over previous
//
#include <hip/hip_runtime.h>

// ---------------- problem constants ----------------
#define C_   64
#define U_   5
#define V_   5
#define H_   128
#define W_   128
#define NH_  4
#define HD_  16
#define WSZ  8
#define S_   64        // tokens per window
#define HW   16384     // H*W
#define UV   25        // U*V
#define POS  409600    // UV*HW, per-channel spatial size
#define TOT  26214400  // C_*POS
#define C4_  256

typedef unsigned short u16;
typedef unsigned int   u32;

// bf16 <-> fp32 helpers (raw bit manipulation, round-to-nearest-even)
__device__ __forceinline__ float us2f(u16 h){ return __uint_as_float(((u32)h)<<16); }
__device__ __forceinline__ u16 f2us(float f){
  u32 u = __float_as_uint(f);
  return (u16)((u + 0x7fffu + ((u>>16)&1u))>>16);
}
__device__ __forceinline__ void up2(u32 w, float&a, float&b){
  a = __uint_as_float(w<<16); b = __uint_as_float(w & 0xffff0000u);
}
__device__ __forceinline__ float silu_f(float x){ return x/(1.f+__expf(-x)); }

// ---------------- K1: LayerNorm over C (norm1) : x(f32) -> t(bf16, pools only) ----
__global__ __launch_bounds__(256,2) void k_ln1(const float* __restrict__ x,
                                               const float* __restrict__ w,
                                               const float* __restrict__ b,
                                               u16* __restrict__ t){
  int p = blockIdx.x*256 + threadIdx.x;        // 0..409599
  float v[64]; float s=0.f, sq=0.f;
  #pragma unroll
  for(int c=0;c<64;c++){ float f = x[c*POS+p]; v[c]=f; s+=f; sq+=f*f; }
  float mu = s*(1.f/64.f);
  float var = sq*(1.f/64.f) - mu*mu;
  float r = rsqrtf(var + 1e-5f);
  #pragma unroll
  for(int c=0;c<64;c++){
    t[c*POS+p] = f2us((v[c]-mu)*r*w[c] + b[c]);
  }
}

// ---------------- K7: LayerNorm over C (norm2) : x2(f32) -> t2(bf16) ----------------
__global__ __launch_bounds__(256,2) void k_ln2(const float* __restrict__ x2,
                                               const float* __restrict__ w,
                                               const float* __restrict__ b,
                                               u16* __restrict__ t2){
  int p = blockIdx.x*256 + threadIdx.x;
  float v[64]; float s=0.f, sq=0.f;
  #pragma unroll
  for(int c=0;c<64;c++){ float f = x2[c*POS+p]; v[c]=f; s+=f; sq+=f*f; }
  float mu = s*(1.f/64.f);
  float var = sq*(1.f/64.f) - mu*mu;
  float r = rsqrtf(var + 1e-5f);
  #pragma unroll
  for(int c=0;c<64;c++){
    t2[c*POS+p] = f2us((v[c]-mu)*r*w[c] + b[c]);
  }
}

// ---------------- K2a: pool over (u,v) -> P_hw[c][h][w] (raw sums) ----------------
__global__ void k_pool_hw(const u16* __restrict__ t, float* __restrict__ P){
  int idx = blockIdx.x*256 + threadIdx.x;      // < 64*16384
  int c = idx>>14, hw = idx & 16383;
  const u16* base = t + c*POS + hw;
  float s = 0.f;
  #pragma unroll
  for(int uv=0; uv<25; uv++) s += us2f(base[uv*HW]);
  P[idx] = s;
}

// ---------------- K2b: pool over (v,w) -> P_hu[c][u][h] ----------------
__global__ void k_pool_hu(const u16* __restrict__ t, float* __restrict__ P){
  int g = blockIdx.x*256 + threadIdx.x;
  int wid = g>>6, lane = g&63;                 // wid < 40960
  int c = wid/640, rem = wid - c*640;
  int u = rem>>7, h = rem&127;
  const u16* base = t + c*POS + u*5*HW + h*128;
  float s = 0.f;
  #pragma unroll
  for(int v=0;v<5;v++){ s += us2f(base[v*HW+lane]) + us2f(base[v*HW+lane+64]); }
  for(int off=32; off; off>>=1) s += __shfl_down(s, off);
  if(lane==0) P[wid] = s;
}

// ---------------- K2c: pool over (u,h) -> P_vw[c][v][w] (direct reduction) --------
__global__ void k_pool_vw(const u16* __restrict__ t, float* __restrict__ P){
  int bid = blockIdx.x;                        // 320 = 64*5
  int c = bid/5, v = bid - c*5;
  int w = threadIdx.x;                         // 128 threads
  float s = 0.f;
  for(int u=0;u<5;u++){
    const u16* base = t + c*POS + (u*5+v)*HW + w;
    for(int h=0;h<128;h++) s += us2f(base[h*128]);
  }
  P[(c*5+v)*128 + w] = s;
}

// ---------------- K2d: pool over (h,w) -> P_uv[c][u][v] ----------------
__global__ void k_pool_uv(const u16* __restrict__ t, float* __restrict__ P){
  int g = blockIdx.x*256 + threadIdx.x;
  int wid = g>>6, lane = g&63;                 // wid < 1600
  int c = wid/25, rem = wid - c*25;
  const u16* base = t + c*POS + rem*HW;
  float s = 0.f;
  #pragma unroll 8
  for(int k=0;k<256;k++) s += us2f(base[lane + k*64]);
  for(int off=32; off; off>>=1) s += __shfl_down(s, off);
  if(lane==0) P[wid] = s;
}

// ---------------- K3: MCA fused conv1 -> silu -> conv2 -> head conv -> fields ----------
__global__ __launch_bounds__(256,1) void k_mca(
    const float* __restrict__ Phw, const float* __restrict__ Phu,
    const float* __restrict__ Pvw, const float* __restrict__ Puv,
    const float* __restrict__ w1, const float* __restrict__ b1,
    const float* __restrict__ w2, const float* __restrict__ b2,
    const float* __restrict__ fw, const float* __restrict__ fb,
    float* __restrict__ F0, float* __restrict__ F1,
    float* __restrict__ F2, float* __restrict__ F3){
  __shared__ float W1s[4096], W2s[4096];
  for(int i=threadIdx.x;i<4096;i+=256){ W1s[i]=w1[i]; W2s[i]=w2[i]; }
  __syncthreads();
  int pos = blockIdx.x*256 + threadIdx.x;
  if(pos >= 133*133) return;
  int r = pos/133, cc = pos - r*133;

  float y1[64];
  #pragma unroll
  for(int o=0;o<64;o++) y1[o] = b1[o];
  for(int c=0;c<64;c++){
    float in;
    if(r<128){
      if(cc<128) in = Phw[(c<<14)+(r<<7)+cc]*(1.f/25.f);
      else       in = Phu[(c*5+(cc-128))*128 + r]*(1.f/640.f);
    } else {
      if(cc<128) in = Pvw[(c*5+(r-128))*128 + cc]*(1.f/640.f);
      else       in = Puv[c*25 + (cc-128)*5 + (r-128)]*(1.f/16384.f);
    }
    #pragma unroll
    for(int o=0;o<64;o++) y1[o] += W1s[o*64+c]*in;
  }
  float y2[64];
  #pragma unroll
  for(int o=0;o<64;o++) y2[o] = b2[o];
  for(int c=0;c<64;c++){
    float v = silu_f(y1[c]);
    #pragma unroll
    for(int o=0;o<64;o++) y2[o] += W2s[o*64+c]*v;
  }
  int hidx, idx0, stride_o; float* dst;
  if(r<128){
    if(cc<128){ hidx=0; dst=F0; idx0=(r<<7)+cc;            stride_o=16384; }
    else      { hidx=2; dst=F2; idx0=(cc-128)*128 + r;     stride_o=640;   }
  } else {
    if(cc<128){ hidx=3; dst=F3; idx0=(r-128)*128 + cc;     stride_o=640;   }
    else      { hidx=1; dst=F1; idx0=(cc-128)*5 + (r-128); stride_o=25;    }
  }
  const float* fwh = fw + hidx*4096;
  for(int o=0;o<64;o++){
    float f = fb[hidx*64+o];
    #pragma unroll
    for(int c=0;c<64;c++) f += fwh[o*64+c]*y2[c];
    dst[o*stride_o + idx0] = f;
  }
}

// ---------------- K5: attention bias gather -> Bt[h][key][query] ----------------
__global__ void k_bias(const int* __restrict__ rpi, const float* __restrict__ tab,
                       float* __restrict__ Bt){
  int idx = blockIdx.x*256 + threadIdx.x;      // < 4096, idx = i*64 + t (i=query)
  int i = idx>>6, tk = idx&63;
  int ri = rpi[idx];
  #pragma unroll
  for(int h=0;h<4;h++) Bt[h*4096 + tk*64 + i] = tab[ri*4+h];
}

// ---------------- K5b: pre-transpose qkv weights -> qkvT[(h*64+c)*48+dd] -------
__global__ void k_wt(const float* __restrict__ qkvw, float* __restrict__ qkvT){
  int i = blockIdx.x*256 + threadIdx.x;        // < 12288
  int h = i/3072, rem = i - h*3072;
  int c = rem/48, dd = rem - c*48;
  qkvT[i] = qkvw[(h*48+dd)*64 + c];
}

// ---------------- K4: x2 = x + LN1(x)*A  (fused-LN MCA combine, all fp32) -------
__global__ __launch_bounds__(256) void k_combine(
    const float* __restrict__ x,
    const float* __restrict__ n1w, const float* __restrict__ n1b,
    const float* __restrict__ F0, const float* __restrict__ F1,
    const float* __restrict__ F2, const float* __restrict__ F3,
    float* __restrict__ x2){
  int p = blockIdx.x*256 + threadIdx.x;        // < 409600
  float v[64]; float s=0.f, sq=0.f;
  #pragma unroll
  for(int c=0;c<64;c++){ float f = x[c*POS+p]; v[c]=f; s+=f; sq+=f*f; }
  float mu = s*(1.f/64.f);
  float r = rsqrtf(sq*(1.f/64.f) - mu*mu + 1e-5f);
  int uvi = p>>14, hw = p & 16383;
  int u = uvi/5, vv = uvi - 5*u;
  int h = hw>>7, w = hw & 127;
  #pragma unroll
  for(int c=0;c<64;c++){
    float t = (v[c]-mu)*r*n1w[c] + n1b[c];
    float A = F0[(c<<14)+hw] + F1[c*25+uvi] + F2[(c*5+u)*128+h] + F3[(c*5+vv)*128+w];
    x2[c*POS+p] = v[c] + t*A;
  }
}

// ---------------- K6: shifted window attention (fp32, in-kernel LN), += x2 ------
__global__ __launch_bounds__(256) void k_attn(
    const float* __restrict__ x,
    const float* __restrict__ n1w, const float* __restrict__ n1b,
    const float* __restrict__ qkvT, const float* __restrict__ qkvb,
    const float* __restrict__ projw, const float* __restrict__ projb,
    const float* __restrict__ Bt, float* __restrict__ x2){
  __shared__ float xws[64*68];                 // [tok][c] raw->normed, reused as ao
  __shared__ float kvu[8*64*16];               // [k/v][head][tok][d]
  __shared__ float ms[64], rs[64], wn[64], bn[64];
  int tid = threadIdx.x;
  int wid = blockIdx.x;
  int uv = wid>>8; int u = uv/5, v = uv - 5*u;
  int hb = (wid>>4)&15, wb = wid&15;
  const float* xbase = x + (u*5+v)*HW;

  if(tid<64){ wn[tid] = n1w[tid]; bn[tid] = n1b[tid]; }
  // stage raw x window (roll +4,+4 applied at gather)
  #pragma unroll
  for(int k2=0;k2<16;k2++){
    int lin = k2*256 + tid;
    int c = lin>>6, tok = lin&63;
    int ti = tok>>3, tj = tok&7;
    int hs = (hb*8+ti-4)&127, ws2 = (wb*8+tj-4)&127;
    xws[tok*68+c] = xbase[c*POS + hs*128 + ws2];
  }
  __syncthreads();
  // per-token LN stats
  if(tid<64){
    float s=0.f, sq=0.f;
    #pragma unroll
    for(int c=0;c<64;c++){ float f = xws[tid*68+c]; s+=f; sq+=f*f; }
    float mu = s*(1.f/64.f);
    ms[tid] = mu;
    rs[tid] = rsqrtf(sq*(1.f/64.f) - mu*mu + 1e-5f);
  }
  __syncthreads();
  // normalize in place
  #pragma unroll
  for(int k2=0;k2<16;k2++){
    int lin = k2*256 + tid;
    int c = lin>>6, tok = lin&63;
    xws[tok*68+c] = (xws[tok*68+c]-ms[tok])*rs[tok]*wn[c] + bn[c];
  }
  __syncthreads();                             // sync: tokens ready

  int h = tid>>6, lane = tid&63;               // head, token
  int hu_ = __builtin_amdgcn_readfirstlane(h); // wave-uniform head for weights
  float A[48];
  #pragma unroll
  for(int j=0;j<48;j++) A[j] = qkvb[hu_*48+j];
  const float* wT = qkvT + hu_*3072;           // [(c)*48+dd]
  for(int c=0;c<64;c++){
    float xc = xws[lane*68+c];
    const float* wr = wT + c*48;               // wave-uniform, cached
    #pragma unroll
    for(int j=0;j<48;j++) A[j] += xc*wr[j];
  }
  float q[16];
  #pragma unroll
  for(int d=0;d<16;d++) q[d] = A[d];
  #pragma unroll
  for(int d=0;d<16;d++){
    kvu[(h*64+lane)*16 + d]     = A[16+d];     // k
    kvu[((4+h)*64+lane)*16 + d] = A[32+d];     // v
  }
  __syncthreads();                             // kv ready; xws input no longer needed

  // scores + softmax (query = lane)
  float s[64]; float mx = -1e30f;
  #pragma unroll
  for(int tk=0;tk<64;tk++){
    const float4* kp = (const float4*)&kvu[(h*64+tk)*16];
    float a = 0.f;
    #pragma unroll
    for(int g4=0; g4<4; g4++){
      float4 kk = kp[g4];
      a += q[g4*4+0]*kk.x + q[g4*4+1]*kk.y + q[g4*4+2]*kk.z + q[g4*4+3]*kk.w;
    }
    a = a*0.25f + Bt[h*4096 + tk*64 + lane];
    s[tk] = a; mx = fmaxf(mx, a);
  }
  float l = 0.f;
  #pragma unroll
  for(int tk=0;tk<64;tk++){ float e = __expf(s[tk]-mx); s[tk]=e; l+=e; }
  float inv = 1.f/l;
  float o[16];
  #pragma unroll
  for(int d=0;d<16;d++) o[d] = 0.f;
  #pragma unroll
  for(int tk=0;tk<64;tk++){
    const float4* vp = (const float4*)&kvu[((4+h)*64+tk)*16];
    float pp = s[tk];
    #pragma unroll
    for(int g4=0; g4<4; g4++){
      float4 vv4 = vp[g4];
      o[g4*4+0] += pp*vv4.x; o[g4*4+1] += pp*vv4.y;
      o[g4*4+2] += pp*vv4.z; o[g4*4+3] += pp*vv4.w;
    }
  }
  #pragma unroll
  for(int d=0;d<16;d++) xws[lane*68 + h*16+d] = o[d]*inv;   // ao (c = h*16+d)
  __syncthreads();                             // ao ready

  // projection + scatter-add into x2 (inverse roll at write)
  int tok = tid&63, cg = tid>>6;
  int cgs = __builtin_amdgcn_readfirstlane(cg);
  float xin2[64];
  #pragma unroll
  for(int k2=0;k2<64;k2++) xin2[k2] = xws[tok*68+k2];
  int ti = tok>>3, tj = tok&7;
  int hf = (hb*8+ti-4)&127, wf_ = (wb*8+tj-4)&127;
  float* xb = x2 + (u*5+v)*HW + hf*128 + wf_;
  for(int cq=0;cq<16;cq++){
    int c = cgs*16+cq;
    float a = projb[c];
    const float* pw = projw + c*64;            // wave-uniform rows, cached
    #pragma unroll
    for(int k2=0;k2<64;k2++) a += xin2[k2]*pw[k2];
    xb[c*POS] += a;
  }
}

// ---------------- K8 v3: fused MBConv + residual, fp32 LDS, conflict-free ------
// Reference semantic (verified round 5): x6.reshape(B*U*V, C, H, W) is a flat
// plane regrouping — batch n uses planes [n*64, n*64+64). Addressing (n*64+c)*HW.
// v3: halo tile + expanded activations staged in FP32 LDS (bf16 unpack happens
// once at staging, not per-FMA; round-6 profile showed ~50% of expand VALU was
// up2 unpack and 5.5M 8-way LDS bank conflicts from the 36-dword row stride).
// t2s row stride = 68 dwords: 272B = 16B-aligned (ds_read_b128) and 4-bank
// stride -> with 16 pg-lanes x 4 og-broadcast = 2-way aliasing = free (m136).
// w2/dw/db/b2 read via wave-uniform scalar loads (readfirstlane'd cg) instead
// of LDS to keep total LDS at 52.8KB -> 3 blocks/CU.
#define OCB 16
__global__ __launch_bounds__(256,3) void k_mbconv(
    const u16* __restrict__ t2, const float* x2,
    const float* __restrict__ w1, const float* __restrict__ b1,
    const float* __restrict__ dw, const float* __restrict__ db,
    const float* __restrict__ w2, const float* __restrict__ b2,
    float* out){
  __shared__ float t2s[144*68];    // 12x12 halo, [p][c] fp32, stride 68 dw
  __shared__ float y1s[16*145];    // expanded+silu on halo, [o][p]
  __shared__ float y2s[64*17];     // dw+silu output, [pix][o] padded
  int tid = threadIdx.x;
  int n = blockIdx.x >> 8, tile = blockIdx.x & 255;   // 25 batches x 256 tiles
  int h0 = (tile>>4)<<3, w0 = (tile&15)<<3;
  const u16* tb = t2 + n*64*HW;

  // stage halo tile (144 pos x 64 ch), bf16 -> fp32 once
  for(int L=tid; L<9216; L+=256){
    int c = L/144, p = L - c*144;
    int rr = p/12, pc = p - rr*12;
    int hh = h0-2+rr, ww = w0-2+pc;
    float val = 0.f;
    if(((unsigned)hh<128u)&&((unsigned)ww<128u)) val = us2f(tb[c*HW + hh*128 + ww]);
    t2s[p*68 + c] = val;
  }
  float acc[16];
  #pragma unroll
  for(int i=0;i<16;i++) acc[i]=0.f;
  int pix = tid & 63, cg = tid >> 6;    // dw/proj mapping (cg wave-uniform)
  int cgu = __builtin_amdgcn_readfirstlane(cg);
  int r = pix>>3, cc = pix&7;
  int og = tid >> 4, pg = tid & 15;     // expand mapping (16 och x 16 pos-lanes)
  __syncthreads();

  for(int oc0=0; oc0<256; oc0+=OCB){
    // expand 1x1 + silu on halo: thread (og,pg) does positions pg+16j, j<9
    {
      float wr[64];
      const float4* wrow = (const float4*)(w1 + (oc0+og)*64);  // L1/L2-resident
      #pragma unroll
      for(int q=0;q<16;q++){
        float4 f4 = wrow[q];
        wr[4*q]=f4.x; wr[4*q+1]=f4.y; wr[4*q+2]=f4.z; wr[4*q+3]=f4.w;
      }
      float bo = b1[oc0+og];
      #pragma unroll
      for(int j=0;j<9;j++){
        int p = pg + 16*j;               // covers 0..143 exactly
        int rr = p/12, pc = p - rr*12;
        int hh = h0-2+rr, ww = w0-2+pc;
        bool inimg = ((unsigned)hh<128u)&&((unsigned)ww<128u);
        const float4* row = (const float4*)(t2s + p*68);  // 272B rows, 16B aligned
        float a = bo;
        #pragma unroll
        for(int q=0;q<16;q++){
          float4 f4 = row[q];
          a += wr[4*q]*f4.x + wr[4*q+1]*f4.y + wr[4*q+2]*f4.z + wr[4*q+3]*f4.w;
        }
        y1s[og*145 + p] = inimg ? silu_f(a) : 0.f;   // post-silu zero pad
      }
    }
    __syncthreads();

    // depthwise 5x5 + silu -> y2s: thread (pix,cg) does o = cg+4*qq
    #pragma unroll
    for(int qq=0;qq<4;qq++){
      int o = cgu + 4*qq;                       // wave-uniform channel
      const float* dwp = dw + (oc0+o)*25;       // -> s_load
      float s = 0.f;
      #pragma unroll
      for(int kh=0;kh<5;kh++){
        #pragma unroll
        for(int kw=0;kw<5;kw++)
          s += y1s[o*145 + (r+kh)*12 + (cc+kw)] * dwp[kh*5 + kw];
      }
      y2s[pix*17 + o] = silu_f(s + db[oc0+o]);
    }
    __syncthreads();

    // project: thread (pix,cg) accumulates its 16 output channels;
    // w2 rows are wave-uniform -> scalar loads, no LDS staging needed
    #pragma unroll
    for(int cq=0;cq<16;cq++){
      const float* w2r = w2 + (cgu*16+cq)*256 + oc0;   // -> s_load_dwordx4 x4
      float a = acc[cq];
      #pragma unroll
      for(int o=0;o<OCB;o++) a += w2r[o]*y2s[pix*17 + o];
      acc[cq] = a;
    }
    __syncthreads();
  }
  int gb = (h0+r)*128 + (w0+cc);
  #pragma unroll
  for(int cq=0;cq<16;cq++){
    int c = cgu*16+cq;
    int g = (n*64+c)*HW + gb;
    out[g] = acc[cq] + b2[c] + x2[g];
  }
}

// ---------------- workspace layout (bytes), total 61,600,256 ----------------
static const size_t OFF_T   = 0;             // u16  t / t2 (reused)   52,428,800
static const size_t OFF_PHW = 52428800;      // f32  pool hw            4,194,304
static const size_t OFF_PHU = 56623104;      // f32  pool hu              163,840
static const size_t OFF_PVW = 56786944;      // f32  pool vw              163,840
static const size_t OFF_PUV = 56950784;      // f32  pool uv                6,400
static const size_t OFF_F0  = 56957184;      // f32  field hw           4,194,304
static const size_t OFF_F2  = 61151488;      // f32  field uh             163,840
static const size_t OFF_F3  = 61315328;      // f32  field vw             163,840
static const size_t OFF_F1  = 61479168;      // f32  field uv               6,400
static const size_t OFF_BT  = 61485568;      // f32  attn bias             65,536
static const size_t OFF_QT  = 61551104;      // f32  qkvT                  49,152

extern "C" void kernel_launch(void* const* d_in, const int* in_sizes, int n_in,
                              void* d_out, int out_size, void* d_ws, size_t ws_size,
                              hipStream_t stream){
  (void)in_sizes; (void)n_in; (void)out_size; (void)ws_size;
  const float* x     = (const float*)d_in[0];
  const float* n1w   = (const float*)d_in[1];
  const float* n1b   = (const float*)d_in[2];
  const float* n2w   = (const float*)d_in[3];
  const float* n2b   = (const float*)d_in[4];
  const float* qkvw  = (const float*)d_in[5];
  const float* qkvb  = (const float*)d_in[6];
  const float* projw = (const float*)d_in[7];
  const float* projb = (const float*)d_in[8];
  const float* rpbt  = (const float*)d_in[9];
  const int*   rpi   = (const int*)d_in[10];
  const float* mw1   = (const float*)d_in[11];
  const float* mb1   = (const float*)d_in[12];
  const float* mw2   = (const float*)d_in[13];
  const float* mb2   = (const float*)d_in[14];
  const float* mfw   = (const float*)d_in[15];
  const float* mfb   = (const float*)d_in[16];
  const float* bw1   = (const float*)d_in[17];
  const float* bb1   = (const float*)d_in[18];
  const float* bdw   = (const float*)d_in[19];
  const float* bdb   = (const float*)d_in[20];
  const float* bw2   = (const float*)d_in[21];
  const float* bb2   = (const float*)d_in[22];

  char* ws = (char*)d_ws;
  u16*   t   = (u16*)  (ws + OFF_T);
  float* Phw = (float*)(ws + OFF_PHW);
  float* Phu = (float*)(ws + OFF_PHU);
  float* Pvw = (float*)(ws + OFF_PVW);
  float* Puv = (float*)(ws + OFF_PUV);
  float* F0  = (float*)(ws + OFF_F0);
  float* F1  = (float*)(ws + OFF_F1);
  float* F2  = (float*)(ws + OFF_F2);
  float* F3  = (float*)(ws + OFF_F3);
  float* Bt  = (float*)(ws + OFF_BT);
  float* qT  = (float*)(ws + OFF_QT);
  float* x2  = (float*)d_out;    // f32 residual accumulator lives in d_out
  float* outp= (float*)d_out;

  // 1) t = LN1(x) (bf16, pool consumption only)
  k_ln1<<<1600,256,0,stream>>>(x, n1w, n1b, t);
  // 2) pools of t
  k_pool_hw<<<4096,256,0,stream>>>(t, Phw);
  k_pool_hu<<<10240,256,0,stream>>>(t, Phu);
  k_pool_vw<<<320,128,0,stream>>>(t, Pvw);
  k_pool_uv<<<400,256,0,stream>>>(t, Puv);
  // 3) MCA convs -> gate fields
  k_mca<<<70,256,0,stream>>>(Phw,Phu,Pvw,Puv, mw1,mb1,mw2,mb2, mfw,mfb, F0,F1,F2,F3);
  // 4) attention bias table + qkv weight transpose
  k_bias<<<16,256,0,stream>>>(rpi, rpbt, Bt);
  k_wt<<<48,256,0,stream>>>(qkvw, qT);
  // 5) x2 = x + LN1(x)*A  (fused LN, pure write of all of d_out)
  k_combine<<<1600,256,0,stream>>>(x, n1w, n1b, F0,F1,F2,F3, x2);
  // 6) x2 += window_attn(LN1(x))  (fp32, in-kernel LN; unique-writer RMW)
  k_attn<<<6400,256,0,stream>>>(x, n1w, n1b, qT, qkvb, projw, projb, Bt, x2);
  // 7) t2 = LN2(x2)   (t buffer reused)
  k_ln2<<<1600,256,0,stream>>>(x2, n2w, n2b, t);
  // 8) out = x2 + mbconv(t2)  (fp32-LDS conflict-free v3, in-place on d_out)
  k_mbconv<<<6400,256,0,stream>>>(t, x2, bw1,bb1, bdw,bdb, bw2,bb2, outp);
}